// Round 13
// baseline (371.223 us; speedup 1.0000x reference)
//
#include <hip/hip_runtime.h>

typedef unsigned short u16;
typedef unsigned int u32;
typedef __attribute__((ext_vector_type(8))) short bf16x8;
typedef __attribute__((ext_vector_type(4))) float f32x4;
typedef __attribute__((ext_vector_type(4))) u32 u32x4;

#define DEV __device__ __forceinline__
#define MFMA16(a, b, c) __builtin_amdgcn_mfma_f32_16x16x32_bf16(a, b, c, 0, 0, 0)

DEV u16 f2bf(float f) {
  u32 u = __float_as_uint(f);
  u32 r = (u + 0x7fffu + ((u >> 16) & 1u)) >> 16;
  return (u16)r;
}

DEV void async16(const void* g, void* l) {
  __builtin_amdgcn_global_load_lds((const __attribute__((address_space(1))) u32*)g,
                                   (__attribute__((address_space(3))) u32*)l, 16, 0, 0);
}

// ---------------- weight transpose+convert: fp32 [K,N] -> bf16 [N,K] ----------------
__global__ __launch_bounds__(256)
void wt_transpose(const float* __restrict__ w, u16* __restrict__ wt, int K, int N) {
  __shared__ float tile[32][33];
  int n0 = blockIdx.x * 32;
  int k0 = blockIdx.y * 32;
  int tx = threadIdx.x;   // 0..31
  int ty = threadIdx.y;   // 0..7
#pragma unroll
  for (int i = 0; i < 4; ++i)
    tile[ty + 8 * i][tx] = w[(size_t)(k0 + ty + 8 * i) * N + n0 + tx];
  __syncthreads();
#pragma unroll
  for (int i = 0; i < 4; ++i) {
    int n = ty + 8 * i;
    wt[(size_t)(n0 + n) * K + k0 + tx] = f2bf(tile[tx][n]);
  }
}

// ---------------- LayerNorm: fp32 row -> bf16 row ----------------
__global__ __launch_bounds__(256)
void ln_kernel(const float* __restrict__ x, const float* __restrict__ g,
               const float* __restrict__ b, u16* __restrict__ out) {
  int row = blockIdx.x;
  int tid = threadIdx.x;
  const float4* xr = (const float4*)(x + (size_t)row * 1024);
  float4 v = xr[tid];
  float s = v.x + v.y + v.z + v.w;
  float ss = v.x * v.x + v.y * v.y + v.z * v.z + v.w * v.w;
#pragma unroll
  for (int o = 32; o > 0; o >>= 1) {
    s += __shfl_down(s, o);
    ss += __shfl_down(ss, o);
  }
  __shared__ float ps[4], pss[4];
  if ((tid & 63) == 0) { ps[tid >> 6] = s; pss[tid >> 6] = ss; }
  __syncthreads();
  s = ps[0] + ps[1] + ps[2] + ps[3];
  ss = pss[0] + pss[1] + pss[2] + pss[3];
  float mu = s * (1.0f / 1024.0f);
  float var = ss * (1.0f / 1024.0f) - mu * mu;
  float rs = rsqrtf(var + 1e-5f);
  float4 gg = ((const float4*)g)[tid];
  float4 bb = ((const float4*)b)[tid];
  ushort4 ov;
  ov.x = f2bf((v.x - mu) * rs * gg.x + bb.x);
  ov.y = f2bf((v.y - mu) * rs * gg.y + bb.y);
  ov.z = f2bf((v.z - mu) * rs * gg.z + bb.z);
  ov.w = f2bf((v.w - mu) * rs * gg.w + bb.w);
  *(ushort4*)(out + (size_t)row * 1024 + tid * 4) = ov;
}

// ---------------- GEMM 128x128 tile, BK=64, 4 waves, swizzled LDS, XCD m-stripes --------
// EPI 0: QKV scatter (V written DIRECTLY transposed to [bh][64][2048]).
// EPI 1: fp32 out = acc+bias+res. EPI 2: tanh-form GELU -> bf16.
template <int EPI>
__global__ __launch_bounds__(256, 4)
void gemm128(const u16* __restrict__ A, const u16* __restrict__ Bt,
             const float* __restrict__ bias, int M, int N, int K,
             float* __restrict__ outf, u16* __restrict__ outb,
             const float* __restrict__ res,
             u16* __restrict__ qp, u16* __restrict__ kp, u16* __restrict__ vp) {
  __shared__ char lds[32768];          // A tile 16KB @0, B tile 16KB @16384
  const int tid = threadIdx.x;
  const int lane = tid & 63, wid = tid >> 6;
  const int wr = wid >> 1, wc = wid & 1;
  const int lr = lane & 15, hi = lane >> 4;
  const int swz = (lr & 7) << 4;

  // XCD m-stripe remap (bijective; XCD = lin%8 round-robin; gridDim.y == 64).
  const int nbx = gridDim.x;
  int lin = blockIdx.x + nbx * blockIdx.y;
  int xcd = lin & 7, j = lin >> 3;
  int bx = j % nbx;
  int by = xcd * 8 + j / nbx;

  const long m0 = (long)by * 128;
  const long n0 = (long)bx * 128;
  const long ldb = (long)K * 2;
  const char* Abase = (const char*)A + m0 * ldb;
  const char* Bbase = (const char*)Bt + n0 * ldb;

  f32x4 acc[4][4];
#pragma unroll
  for (int i = 0; i < 4; ++i)
#pragma unroll
    for (int jj = 0; jj < 4; ++jj) acc[i][jj] = (f32x4)0.0f;

  auto stage = [&](const char* base, int kt, int dst) {
#pragma unroll
    for (int l = 0; l < 4; ++l) {
      int c = (wid * 4 + l) * 64 + lane;     // 16B-chunk index 0..1023
      int r = c >> 3, ch = c & 7;            // row 0..127, chunk-in-row 0..7
      async16(base + (long)kt * 128 + (long)r * ldb + ((ch * 16) ^ ((r & 7) << 4)),
              lds + dst + (wid * 4 + l) * 1024);
    }
  };
  auto rdA = [&](int mi, int kk) {
    int rr = wr * 64 + mi * 16 + lr;
    return *(const bf16x8*)(lds + rr * 128 + ((kk * 64 + hi * 16) ^ swz));
  };
  auto rdB = [&](int ni, int kk) {
    int rr = wc * 64 + ni * 16 + lr;
    return *(const bf16x8*)(lds + 16384 + rr * 128 + ((kk * 64 + hi * 16) ^ swz));
  };

  const int NT = K >> 6;
  for (int kt = 0; kt < NT; ++kt) {
    stage(Abase, kt, 0);
    stage(Bbase, kt, 16384);
    __syncthreads();
#pragma unroll
    for (int kk = 0; kk < 2; ++kk) {
      bf16x8 a[4], b[4];
#pragma unroll
      for (int mi = 0; mi < 4; ++mi) a[mi] = rdA(mi, kk);
#pragma unroll
      for (int ni = 0; ni < 4; ++ni) b[ni] = rdB(ni, kk);
      __builtin_amdgcn_s_setprio(1);
#pragma unroll
      for (int mi = 0; mi < 4; ++mi)
#pragma unroll
        for (int ni = 0; ni < 4; ++ni)
          acc[mi][ni] = MFMA16(a[mi], b[ni], acc[mi][ni]);
      __builtin_amdgcn_s_setprio(0);
    }
    __syncthreads();
  }

  int rgrp = hi * 4;
#pragma unroll
  for (int mi = 0; mi < 4; ++mi) {
#pragma unroll
    for (int ni = 0; ni < 4; ++ni) {
      long col = n0 + wc * 64 + ni * 16 + lr;
      float bv = bias[col];
#pragma unroll
      for (int r = 0; r < 4; ++r) {
        long row = m0 + wr * 64 + mi * 16 + rgrp + r;
        float c = acc[mi][ni][r] + bv;
        if (EPI == 0) {
          // QKV scatter: col in [0,3072): part=col>>10, head=(col&1023)>>6, dd=col&63
          int part = (int)(col >> 10);
          int hd = (int)(col & 1023);
          long bq = row >> 11;
          long sq = row & 2047;
          long bh = (bq << 4) + (hd >> 6);
          if (part == 0) {
            // q pre-scaled by (1/sqrt(d)) * log2(e) for base-2 online softmax
            qp[(bh * 2048 + sq) * 64 + (hd & 63)] = f2bf(c * 0.18033688f);
          } else if (part == 1) {
            kp[(bh * 2048 + sq) * 64 + (hd & 63)] = f2bf(c);
          } else {
            // V written transposed: [bh][d=64][s=2048]
            vp[(bh << 17) + (long)(hd & 63) * 2048 + sq] = f2bf(c);
          }
        } else if (EPI == 1) {
          long idx = row * (long)N + col;
          outf[idx] = c + res[idx];
        } else {
          float t = c * (2.3022871f + 0.1029445f * c * c);
          float e = __builtin_amdgcn_exp2f(t);
          float gl = c - c / (e + 1.0f);
          outb[row * (long)N + col] = f2bf(gl);
        }
      }
    }
  }
}

// ---------------- Flash attention (causal), QBLK=64 paired q-tiles, base-2 softmax -----
// Pair {31-j (heavy), j (light)}, j=0..15 -> 1024 blocks = 4 blocks/CU (grid was the
// occupancy limiter at QBLK=128). LDS 40KB (K/V dbuf 32KB + P 8KB) -> 4 x 40KB = 160KB.
// Each wave owns 16 q-rows per q-tile. Diagonal mask only at t+1 == ntp.
__global__ __launch_bounds__(256, 4)
void attn_kernel(const u16* __restrict__ q, const u16* __restrict__ k,
                 const u16* __restrict__ vt, u16* __restrict__ outp) {
  __shared__ char ldsK[2][8192];
  __shared__ char ldsV[2][8192];
  __shared__ char ldsP[4][2048];          // per-wave P [16][64] bf16, swizzled
  // XCD swizzle: lin%8 = XCD; bh%8 == XCD so all 16 j-blocks of a bh share an XCD.
  int lin = blockIdx.x + 16 * blockIdx.y;
  int xcd = lin & 7, pos = lin >> 3;      // pos 0..127
  int j = pos >> 3;                       // 0..15
  int bh = ((pos & 7) << 3) | xcd;        // 0..63
  int tid = threadIdx.x, lane = tid & 63, w = tid >> 6;
  const u16* qb = q + (size_t)bh * 131072;
  const u16* kb = k + (size_t)bh * 131072;
  const u16* vb = vt + (size_t)bh * 131072;

  int lr = lane & 15, lg = lane >> 4;
  int swz = (lr & 7) << 4;

  const int qih = 31 - j, qil = j;
  const int NTH = qih + 1;                // 17..32
  const int NTL = qil + 1;                // 1..16

  const bf16x8 ones = (bf16x8)(short)0x3F80;  // bf16 1.0 splat

  bf16x8 qf[2][2];
#pragma unroll
  for (int p = 0; p < 2; ++p) {
    int q0p = (p ? qil : qih) * 64;
    const u16* qr = qb + (size_t)(q0p + w * 16 + lr) * 64 + lg * 8;
    qf[p][0] = *(const bf16x8*)(qr);
    qf[p][1] = *(const bf16x8*)(qr + 32);
  }

  f32x4 o[2][4];
  f32x4 lacc[2];
  float m_run[2][4];
#pragma unroll
  for (int p = 0; p < 2; ++p) {
    lacc[p] = (f32x4)0.0f;
#pragma unroll
    for (int i = 0; i < 4; ++i) {
      o[p][i] = (f32x4)0.0f;
      m_run[p][i] = -1e30f;
    }
  }

  auto stage = [&](int buf, int t) {
    int kv0 = t * 64;
    const char* gk = (const char*)(kb + (size_t)kv0 * 64);
#pragma unroll
    for (int i = 0; i < 2; ++i) {
      int off = i * 4096 + tid * 16;
      int src = off ^ (((off >> 7) & 7) << 4);
      async16(gk + src, &ldsK[buf][i * 4096 + w * 1024]);
    }
#pragma unroll
    for (int i = 0; i < 2; ++i) {
      int vrow = i * 32 + (tid >> 3);
      int cb = ((tid & 7) * 16) ^ ((vrow & 7) << 4);
      async16((const char*)vb + (size_t)vrow * 4096 + (size_t)kv0 * 2 + cb,
              &ldsV[buf][i * 4096 + w * 1024]);
    }
  };

  stage(0, 0);
  __syncthreads();
  int cur = 0;

  for (int t = 0; t < NTH; ++t) {
    if (t + 1 < NTH) stage(cur ^ 1, t + 1);
    int kv0 = t * 64;

#pragma unroll
    for (int p = 0; p < 2; ++p) {
      if (p == 1 && t >= NTL) break;
      int q0p = (p ? qil : qih) * 64;
      int ntp = p ? NTL : NTH;

      // S2 = Q K^T  (base-2 logits)
      f32x4 s[4];
      __builtin_amdgcn_s_setprio(1);
#pragma unroll
      for (int nf = 0; nf < 4; ++nf) {
        s[nf] = (f32x4)0.0f;
#pragma unroll
        for (int ks = 0; ks < 2; ++ks) {
          bf16x8 kf = *(const bf16x8*)(&ldsK[cur][(nf * 16 + lr) * 128 +
                                                 ((ks * 64 + lg * 16) ^ swz)]);
          s[nf] = MFMA16(qf[p][ks], kf, s[nf]);
        }
      }
      __builtin_amdgcn_s_setprio(0);

      // causal mask — only the diagonal tile
      if (t + 1 == ntp) {
#pragma unroll
        for (int nf = 0; nf < 4; ++nf)
#pragma unroll
          for (int r = 0; r < 4; ++r) {
            int qrow = q0p + w * 16 + lg * 4 + r;
            int kvc = kv0 + nf * 16 + lr;
            if (kvc > qrow) s[nf][r] = -1e30f;
          }
      }

      // defer-max: lane-local bound check; full reduce+rescale only on overflow
      float pmx[4];
      bool need = false;
#pragma unroll
      for (int r = 0; r < 4; ++r) {
        pmx[r] = fmaxf(fmaxf(s[0][r], s[1][r]), fmaxf(s[2][r], s[3][r]));
        need = need || (pmx[r] > m_run[p][r] + 11.5f);
      }
      if (__any(need)) {
#pragma unroll
        for (int r = 0; r < 4; ++r) {
          float pm = pmx[r];
#pragma unroll
          for (int m = 1; m < 16; m <<= 1) pm = fmaxf(pm, __shfl_xor(pm, m));
          float mnew = fmaxf(m_run[p][r], pm);
          float al = __builtin_amdgcn_exp2f(m_run[p][r] - mnew);
          m_run[p][r] = mnew;
          lacc[p][r] *= al;
#pragma unroll
          for (int nf = 0; nf < 4; ++nf) o[p][nf][r] *= al;
        }
      }

      // P = exp2(S2 - m); truncation-only bf16
#pragma unroll
      for (int nf = 0; nf < 4; ++nf)
#pragma unroll
        for (int r = 0; r < 4; ++r) {
          float pv = __builtin_amdgcn_exp2f(s[nf][r] - m_run[p][r]);
          int prow = lg * 4 + r;
          int pb = ((nf * 16 + lr) * 2) ^ ((prow & 7) << 4);
          *(u16*)(&ldsP[w][prow * 128 + pb]) = (u16)(__float_as_uint(pv) >> 16);
        }

      // O += P V ; l += P * 1
      __builtin_amdgcn_s_setprio(1);
#pragma unroll
      for (int ks = 0; ks < 2; ++ks) {
        bf16x8 pf = *(const bf16x8*)(&ldsP[w][lr * 128 +
                                             ((ks * 64 + lg * 16) ^ swz)]);
        lacc[p] = MFMA16(pf, ones, lacc[p]);
#pragma unroll
        for (int nf = 0; nf < 4; ++nf) {
          bf16x8 vf = *(const bf16x8*)(&ldsV[cur][(nf * 16 + lr) * 128 +
                                                 ((ks * 64 + lg * 16) ^ swz)]);
          o[p][nf] = MFMA16(pf, vf, o[p][nf]);
        }
      }
      __builtin_amdgcn_s_setprio(0);
    }

    __syncthreads();
    cur ^= 1;
  }

  int b = bh >> 4, h = bh & 15;
#pragma unroll
  for (int p = 0; p < 2; ++p) {
    int q0p = (p ? qil : qih) * 64;
#pragma unroll
    for (int r = 0; r < 4; ++r) {
      int qrow = q0p + w * 16 + lg * 4 + r;
      float inv = 1.0f / lacc[p][r];
      size_t base = ((size_t)(b * 2048 + qrow)) * 1024 + h * 64;
#pragma unroll
      for (int nf = 0; nf < 4; ++nf)
        outp[base + nf * 16 + lr] = f2bf(o[p][nf][r] * inv);
    }
  }
}

// ---------------- launch ----------------
extern "C" void kernel_launch(void* const* d_in, const int* in_sizes, int n_in,
                              void* d_out, int out_size, void* d_ws, size_t ws_size,
                              hipStream_t stream) {
  const float* x      = (const float*)d_in[0];
  const float* ln1_g  = (const float*)d_in[1];
  const float* ln1_b  = (const float*)d_in[2];
  const float* w_attn = (const float*)d_in[3];
  const float* b_attn = (const float*)d_in[4];
  const float* w_proj = (const float*)d_in[5];
  const float* b_proj = (const float*)d_in[6];
  const float* ln2_g  = (const float*)d_in[7];
  const float* ln2_b  = (const float*)d_in[8];
  const float* w_fc   = (const float*)d_in[9];
  const float* b_fc   = (const float*)d_in[10];
  const float* w_fc2  = (const float*)d_in[11];
  const float* b_fc2  = (const float*)d_in[12];
  float* out = (float*)d_out;

  char* ws = (char*)d_ws;
  u16* wt_attn = (u16*)(ws + 0);          //  6291456 B
  u16* wt_proj = (u16*)(ws + 6291456);    //  2097152 B
  u16* wt_fc   = (u16*)(ws + 8388608);    //  8388608 B
  u16* wt_fc2  = (u16*)(ws + 16777216);   //  8388608 B
  u16* xn      = (u16*)(ws + 25165824);   // 16777216 B (LN1 out, reused for LN2 out)
  float* x2    = (float*)(ws + 41943040); // 33554432 B
  char* region = ws + 75497472;           // 83886080 B union region
  u16* qb = (u16*)(region);               // 16 MiB each
  u16* kb = (u16*)(region + 16777216);
  u16* vt = (u16*)(region + 33554432);    // V written directly transposed [bh][64][2048]
  u16* ao = (u16*)(region + 50331648);
  u16* hm = (u16*)(region);               // 64 MiB, overlaps dead q/k/vt

  dim3 tb(32, 8);
  wt_transpose<<<dim3(3072 / 32, 1024 / 32), tb, 0, stream>>>(w_attn, wt_attn, 1024, 3072);
  wt_transpose<<<dim3(1024 / 32, 1024 / 32), tb, 0, stream>>>(w_proj, wt_proj, 1024, 1024);
  wt_transpose<<<dim3(4096 / 32, 1024 / 32), tb, 0, stream>>>(w_fc, wt_fc, 1024, 4096);
  wt_transpose<<<dim3(1024 / 32, 4096 / 32), tb, 0, stream>>>(w_fc2, wt_fc2, 4096, 1024);

  ln_kernel<<<8192, 256, 0, stream>>>(x, ln1_g, ln1_b, xn);

  gemm128<0><<<dim3(3072 / 128, 8192 / 128), 256, 0, stream>>>(
      xn, wt_attn, b_attn, 8192, 3072, 1024,
      nullptr, nullptr, nullptr, qb, kb, vt);

  attn_kernel<<<dim3(16, 64), 256, 0, stream>>>(qb, kb, vt, ao);

  gemm128<1><<<dim3(1024 / 128, 8192 / 128), 256, 0, stream>>>(
      ao, wt_proj, b_proj, 8192, 1024, 1024,
      x2, nullptr, x, nullptr, nullptr, nullptr);

  ln_kernel<<<8192, 256, 0, stream>>>(x2, ln2_g, ln2_b, xn);

  gemm128<2><<<dim3(4096 / 128, 8192 / 128), 256, 0, stream>>>(
      xn, wt_fc, b_fc, 8192, 4096, 1024,
      nullptr, hm, nullptr, nullptr, nullptr, nullptr);

  gemm128<1><<<dim3(1024 / 128, 8192 / 128), 256, 0, stream>>>(
      hm, wt_fc2, b_fc2, 8192, 1024, 4096,
      out, nullptr, x2, nullptr, nullptr, nullptr);
}

// Round 14
// 365.568 us; speedup vs baseline: 1.0155x; 1.0155x over previous
//
#include <hip/hip_runtime.h>

typedef unsigned short u16;
typedef unsigned int u32;
typedef __attribute__((ext_vector_type(8))) short bf16x8;
typedef __attribute__((ext_vector_type(4))) float f32x4;
typedef __attribute__((ext_vector_type(4))) u32 u32x4;

#define DEV __device__ __forceinline__
#define MFMA16(a, b, c) __builtin_amdgcn_mfma_f32_16x16x32_bf16(a, b, c, 0, 0, 0)

DEV u16 f2bf(float f) {
  u32 u = __float_as_uint(f);
  u32 r = (u + 0x7fffu + ((u >> 16) & 1u)) >> 16;
  return (u16)r;
}

DEV void async16(const void* g, void* l) {
  __builtin_amdgcn_global_load_lds((const __attribute__((address_space(1))) u32*)g,
                                   (__attribute__((address_space(3))) u32*)l, 16, 0, 0);
}

// ---------------- weight transpose+convert: fp32 [K,N] -> bf16 [N,K] ----------------
__global__ __launch_bounds__(256)
void wt_transpose(const float* __restrict__ w, u16* __restrict__ wt, int K, int N) {
  __shared__ float tile[32][33];
  int n0 = blockIdx.x * 32;
  int k0 = blockIdx.y * 32;
  int tx = threadIdx.x;   // 0..31
  int ty = threadIdx.y;   // 0..7
#pragma unroll
  for (int i = 0; i < 4; ++i)
    tile[ty + 8 * i][tx] = w[(size_t)(k0 + ty + 8 * i) * N + n0 + tx];
  __syncthreads();
#pragma unroll
  for (int i = 0; i < 4; ++i) {
    int n = ty + 8 * i;
    wt[(size_t)(n0 + n) * K + k0 + tx] = f2bf(tile[tx][n]);
  }
}

// ---------------- LayerNorm: fp32 row -> bf16 row ----------------
__global__ __launch_bounds__(256)
void ln_kernel(const float* __restrict__ x, const float* __restrict__ g,
               const float* __restrict__ b, u16* __restrict__ out) {
  int row = blockIdx.x;
  int tid = threadIdx.x;
  const float4* xr = (const float4*)(x + (size_t)row * 1024);
  float4 v = xr[tid];
  float s = v.x + v.y + v.z + v.w;
  float ss = v.x * v.x + v.y * v.y + v.z * v.z + v.w * v.w;
#pragma unroll
  for (int o = 32; o > 0; o >>= 1) {
    s += __shfl_down(s, o);
    ss += __shfl_down(ss, o);
  }
  __shared__ float ps[4], pss[4];
  if ((tid & 63) == 0) { ps[tid >> 6] = s; pss[tid >> 6] = ss; }
  __syncthreads();
  s = ps[0] + ps[1] + ps[2] + ps[3];
  ss = pss[0] + pss[1] + pss[2] + pss[3];
  float mu = s * (1.0f / 1024.0f);
  float var = ss * (1.0f / 1024.0f) - mu * mu;
  float rs = rsqrtf(var + 1e-5f);
  float4 gg = ((const float4*)g)[tid];
  float4 bb = ((const float4*)b)[tid];
  ushort4 ov;
  ov.x = f2bf((v.x - mu) * rs * gg.x + bb.x);
  ov.y = f2bf((v.y - mu) * rs * gg.y + bb.y);
  ov.z = f2bf((v.z - mu) * rs * gg.z + bb.z);
  ov.w = f2bf((v.w - mu) * rs * gg.w + bb.w);
  *(ushort4*)(out + (size_t)row * 1024 + tid * 4) = ov;
}

// ---------------- V transpose: bf16 [bh][2048][64] -> [bh][64][2048] ----------------
__global__ __launch_bounds__(256)
void v_transpose(const u16* __restrict__ v, u16* __restrict__ vt) {
  __shared__ u16 t[64][72];
  int s0 = blockIdx.x * 64;
  int bh = blockIdx.y;
  int tid = threadIdx.x;
  const u16* src = v + ((size_t)bh * 2048 + s0) * 64;
#pragma unroll
  for (int p = 0; p < 2; ++p) {
    int r = p * 32 + (tid >> 3);
    int c = (tid & 7) * 8;
    u32x4 a = *(const u32x4*)(src + r * 64 + c);
    const u16* pa = (const u16*)&a;
#pragma unroll
    for (int j = 0; j < 8; ++j) t[r][c + j] = pa[j];
  }
  __syncthreads();
  u16* dst = vt + (size_t)bh * 131072 + s0;
#pragma unroll
  for (int p = 0; p < 2; ++p) {
    int d = p * 32 + (tid >> 3);
    int sc = (tid & 7) * 8;
    u32x4 a;
    u16* pa = (u16*)&a;
#pragma unroll
    for (int j = 0; j < 8; ++j) pa[j] = t[sc + j][d];
    *(u32x4*)(dst + (size_t)d * 2048 + sc) = a;
  }
}

// ---------------- GEMM 128x128 tile, BK=64, 4 waves, swizzled LDS, XCD m-stripes --------
// EPI 0: QKV scatter (q/k/v all [bh][s][d] row-major; q pre-scaled by log2e/8).
// EPI 1: fp32 out = acc+bias+res. EPI 2: tanh-form GELU -> bf16.
template <int EPI>
__global__ __launch_bounds__(256, 4)
void gemm128(const u16* __restrict__ A, const u16* __restrict__ Bt,
             const float* __restrict__ bias, int M, int N, int K,
             float* __restrict__ outf, u16* __restrict__ outb,
             const float* __restrict__ res,
             u16* __restrict__ qp, u16* __restrict__ kp, u16* __restrict__ vp) {
  __shared__ char lds[32768];          // A tile 16KB @0, B tile 16KB @16384
  const int tid = threadIdx.x;
  const int lane = tid & 63, wid = tid >> 6;
  const int wr = wid >> 1, wc = wid & 1;
  const int lr = lane & 15, hi = lane >> 4;
  const int swz = (lr & 7) << 4;

  // XCD m-stripe remap (bijective; XCD = lin%8 round-robin; gridDim.y == 64).
  const int nbx = gridDim.x;
  int lin = blockIdx.x + nbx * blockIdx.y;
  int xcd = lin & 7, j = lin >> 3;
  int bx = j % nbx;
  int by = xcd * 8 + j / nbx;

  const long m0 = (long)by * 128;
  const long n0 = (long)bx * 128;
  const long ldb = (long)K * 2;
  const char* Abase = (const char*)A + m0 * ldb;
  const char* Bbase = (const char*)Bt + n0 * ldb;

  f32x4 acc[4][4];
#pragma unroll
  for (int i = 0; i < 4; ++i)
#pragma unroll
    for (int jj = 0; jj < 4; ++jj) acc[i][jj] = (f32x4)0.0f;

  auto stage = [&](const char* base, int kt, int dst) {
#pragma unroll
    for (int l = 0; l < 4; ++l) {
      int c = (wid * 4 + l) * 64 + lane;     // 16B-chunk index 0..1023
      int r = c >> 3, ch = c & 7;            // row 0..127, chunk-in-row 0..7
      async16(base + (long)kt * 128 + (long)r * ldb + ((ch * 16) ^ ((r & 7) << 4)),
              lds + dst + (wid * 4 + l) * 1024);
    }
  };
  auto rdA = [&](int mi, int kk) {
    int rr = wr * 64 + mi * 16 + lr;
    return *(const bf16x8*)(lds + rr * 128 + ((kk * 64 + hi * 16) ^ swz));
  };
  auto rdB = [&](int ni, int kk) {
    int rr = wc * 64 + ni * 16 + lr;
    return *(const bf16x8*)(lds + 16384 + rr * 128 + ((kk * 64 + hi * 16) ^ swz));
  };

  const int NT = K >> 6;
  for (int kt = 0; kt < NT; ++kt) {
    stage(Abase, kt, 0);
    stage(Bbase, kt, 16384);
    __syncthreads();
#pragma unroll
    for (int kk = 0; kk < 2; ++kk) {
      bf16x8 a[4], b[4];
#pragma unroll
      for (int mi = 0; mi < 4; ++mi) a[mi] = rdA(mi, kk);
#pragma unroll
      for (int ni = 0; ni < 4; ++ni) b[ni] = rdB(ni, kk);
      __builtin_amdgcn_s_setprio(1);
#pragma unroll
      for (int mi = 0; mi < 4; ++mi)
#pragma unroll
        for (int ni = 0; ni < 4; ++ni)
          acc[mi][ni] = MFMA16(a[mi], b[ni], acc[mi][ni]);
      __builtin_amdgcn_s_setprio(0);
    }
    __syncthreads();
  }

  int rgrp = hi * 4;
#pragma unroll
  for (int mi = 0; mi < 4; ++mi) {
#pragma unroll
    for (int ni = 0; ni < 4; ++ni) {
      long col = n0 + wc * 64 + ni * 16 + lr;
      float bv = bias[col];
#pragma unroll
      for (int r = 0; r < 4; ++r) {
        long row = m0 + wr * 64 + mi * 16 + rgrp + r;
        float c = acc[mi][ni][r] + bv;
        if (EPI == 0) {
          // QKV scatter: col in [0,3072): part=col>>10, head=(col&1023)>>6, dd=col&63
          int part = (int)(col >> 10);
          int hd = (int)(col & 1023);
          long bq = row >> 11;
          long sq = row & 2047;
          long dst = (((bq << 4) + (hd >> 6)) * 2048 + sq) * 64 + (hd & 63);
          if (part == 0) {
            // q pre-scaled by (1/sqrt(d)) * log2(e) for base-2 online softmax
            qp[dst] = f2bf(c * 0.18033688f);
          } else if (part == 1) {
            kp[dst] = f2bf(c);
          } else {
            vp[dst] = f2bf(c);
          }
        } else if (EPI == 1) {
          long idx = row * (long)N + col;
          outf[idx] = c + res[idx];
        } else {
          float t = c * (2.3022871f + 0.1029445f * c * c);
          float e = __builtin_amdgcn_exp2f(t);
          float gl = c - c / (e + 1.0f);
          outb[row * (long)N + col] = f2bf(gl);
        }
      }
    }
  }
}

// ---------------- Flash attention (causal), QBLK=128 paired q-tiles, base-2 softmax ----
// Pair {15-j (heavy), j (light)}, j=0..7; shared K/V stream; dbuf staging; XOR-swizzled
// LDS; defer-max (THR 11.5 base-2); l via MFMA P*ones; truncation-only P->bf16.
__global__ __launch_bounds__(256, 2)
void attn_kernel(const u16* __restrict__ q, const u16* __restrict__ k,
                 const u16* __restrict__ vt, u16* __restrict__ outp) {
  __shared__ char ldsK[2][8192];
  __shared__ char ldsV[2][8192];
  __shared__ char ldsP[4][4096];
  int lin = blockIdx.x + 8 * blockIdx.y;
  int xcd = lin & 7, pos = lin >> 3;
  int j = pos >> 3;                       // 0..7
  int bh = ((pos & 7) << 3) | xcd;        // 0..63
  int tid = threadIdx.x, lane = tid & 63, w = tid >> 6;
  const u16* qb = q + (size_t)bh * 131072;
  const u16* kb = k + (size_t)bh * 131072;
  const u16* vb = vt + (size_t)bh * 131072;

  int lr = lane & 15, lg = lane >> 4;
  int swz = (lr & 7) << 4;

  const int qih = 15 - j, qil = j;
  const int NTH = 2 * qih + 2;
  const int NTL = 2 * qil + 2;

  const bf16x8 ones = (bf16x8)(short)0x3F80;  // bf16 1.0 splat

  bf16x8 qf[2][2][2];
#pragma unroll
  for (int p = 0; p < 2; ++p) {
    int q0p = (p ? qil : qih) * 128;
#pragma unroll
    for (int fq = 0; fq < 2; ++fq) {
      const u16* qr = qb + (size_t)(q0p + w * 32 + fq * 16 + lr) * 64 + lg * 8;
      qf[p][fq][0] = *(const bf16x8*)(qr);
      qf[p][fq][1] = *(const bf16x8*)(qr + 32);
    }
  }

  f32x4 o[2][2][4];
  f32x4 lacc[2][2];
  float m_run[2][2][4];
#pragma unroll
  for (int p = 0; p < 2; ++p)
#pragma unroll
    for (int fq = 0; fq < 2; ++fq) {
      lacc[p][fq] = (f32x4)0.0f;
#pragma unroll
      for (int i = 0; i < 4; ++i) {
        o[p][fq][i] = (f32x4)0.0f;
        m_run[p][fq][i] = -1e30f;
      }
    }

  auto stage = [&](int buf, int t) {
    int kv0 = t * 64;
    const char* gk = (const char*)(kb + (size_t)kv0 * 64);
#pragma unroll
    for (int i = 0; i < 2; ++i) {
      int off = i * 4096 + tid * 16;
      int src = off ^ (((off >> 7) & 7) << 4);
      async16(gk + src, &ldsK[buf][i * 4096 + w * 1024]);
    }
#pragma unroll
    for (int i = 0; i < 2; ++i) {
      int vrow = i * 32 + (tid >> 3);
      int cb = ((tid & 7) * 16) ^ ((vrow & 7) << 4);
      async16((const char*)vb + (size_t)vrow * 4096 + (size_t)kv0 * 2 + cb,
              &ldsV[buf][i * 4096 + w * 1024]);
    }
  };

  stage(0, 0);
  __syncthreads();
  int cur = 0;

  for (int t = 0; t < NTH; ++t) {
    if (t + 1 < NTH) stage(cur ^ 1, t + 1);
    int kv0 = t * 64;

#pragma unroll
    for (int p = 0; p < 2; ++p) {
      if (p == 1 && t >= NTL) break;
      int q0p = (p ? qil : qih) * 128;
      int ntp = p ? NTL : NTH;

      // S2 = Q K^T  (base-2 logits)
      f32x4 s[2][4];
      __builtin_amdgcn_s_setprio(1);
#pragma unroll
      for (int nf = 0; nf < 4; ++nf) {
#pragma unroll
        for (int fq = 0; fq < 2; ++fq) s[fq][nf] = (f32x4)0.0f;
#pragma unroll
        for (int ks = 0; ks < 2; ++ks) {
          bf16x8 kf = *(const bf16x8*)(&ldsK[cur][(nf * 16 + lr) * 128 +
                                                 ((ks * 64 + lg * 16) ^ swz)]);
#pragma unroll
          for (int fq = 0; fq < 2; ++fq)
            s[fq][nf] = MFMA16(qf[p][fq][ks], kf, s[fq][nf]);
        }
      }
      __builtin_amdgcn_s_setprio(0);

      // causal mask — only the last two tiles of this q-tile touch the diagonal
      if (t + 2 >= ntp) {
#pragma unroll
        for (int fq = 0; fq < 2; ++fq)
#pragma unroll
          for (int nf = 0; nf < 4; ++nf)
#pragma unroll
            for (int r = 0; r < 4; ++r) {
              int qrow = q0p + w * 32 + fq * 16 + lg * 4 + r;
              int kvc = kv0 + nf * 16 + lr;
              if (kvc > qrow) s[fq][nf][r] = -1e30f;
            }
      }

      // defer-max: lane-local bound check; full reduce+rescale only on overflow
      float pmx[2][4];
      bool need = false;
#pragma unroll
      for (int fq = 0; fq < 2; ++fq)
#pragma unroll
        for (int r = 0; r < 4; ++r) {
          pmx[fq][r] = fmaxf(fmaxf(s[fq][0][r], s[fq][1][r]),
                             fmaxf(s[fq][2][r], s[fq][3][r]));
          need = need || (pmx[fq][r] > m_run[p][fq][r] + 11.5f);
        }
      if (__any(need)) {
#pragma unroll
        for (int fq = 0; fq < 2; ++fq)
#pragma unroll
          for (int r = 0; r < 4; ++r) {
            float pm = pmx[fq][r];
#pragma unroll
            for (int m = 1; m < 16; m <<= 1) pm = fmaxf(pm, __shfl_xor(pm, m));
            float mnew = fmaxf(m_run[p][fq][r], pm);
            float al = __builtin_amdgcn_exp2f(m_run[p][fq][r] - mnew);
            m_run[p][fq][r] = mnew;
            lacc[p][fq][r] *= al;
#pragma unroll
            for (int nf = 0; nf < 4; ++nf) o[p][fq][nf][r] *= al;
          }
      }

      // P = exp2(S2 - m); truncation-only bf16 (o/l normalization cancels the bias)
#pragma unroll
      for (int fq = 0; fq < 2; ++fq)
#pragma unroll
        for (int nf = 0; nf < 4; ++nf)
#pragma unroll
          for (int r = 0; r < 4; ++r) {
            float pv = __builtin_amdgcn_exp2f(s[fq][nf][r] - m_run[p][fq][r]);
            int prow = fq * 16 + lg * 4 + r;
            int pb = ((nf * 16 + lr) * 2) ^ ((prow & 7) << 4);
            *(u16*)(&ldsP[w][prow * 128 + pb]) = (u16)(__float_as_uint(pv) >> 16);
          }

      // O += P V ; l += P * 1  (denominator as an extra MFMA column)
      __builtin_amdgcn_s_setprio(1);
#pragma unroll
      for (int ks = 0; ks < 2; ++ks) {
        bf16x8 pf[2];
#pragma unroll
        for (int fq = 0; fq < 2; ++fq)
          pf[fq] = *(const bf16x8*)(&ldsP[w][(fq * 16 + lr) * 128 +
                                             ((ks * 64 + lg * 16) ^ swz)]);
        lacc[p][0] = MFMA16(pf[0], ones, lacc[p][0]);
        lacc[p][1] = MFMA16(pf[1], ones, lacc[p][1]);
#pragma unroll
        for (int nf = 0; nf < 4; ++nf) {
          bf16x8 vf = *(const bf16x8*)(&ldsV[cur][(nf * 16 + lr) * 128 +
                                                 ((ks * 64 + lg * 16) ^ swz)]);
#pragma unroll
          for (int fq = 0; fq < 2; ++fq)
            o[p][fq][nf] = MFMA16(pf[fq], vf, o[p][fq][nf]);
        }
      }
      __builtin_amdgcn_s_setprio(0);
    }

    __syncthreads();
    cur ^= 1;
  }

  int b = bh >> 4, h = bh & 15;
#pragma unroll
  for (int p = 0; p < 2; ++p) {
    int q0p = (p ? qil : qih) * 128;
#pragma unroll
    for (int fq = 0; fq < 2; ++fq)
#pragma unroll
      for (int r = 0; r < 4; ++r) {
        int qrow = q0p + w * 32 + fq * 16 + lg * 4 + r;
        float inv = 1.0f / lacc[p][fq][r];
        size_t base = ((size_t)(b * 2048 + qrow)) * 1024 + h * 64;
#pragma unroll
        for (int nf = 0; nf < 4; ++nf)
          outp[base + nf * 16 + lr] = f2bf(o[p][fq][nf][r] * inv);
      }
  }
}

// ---------------- launch ----------------
extern "C" void kernel_launch(void* const* d_in, const int* in_sizes, int n_in,
                              void* d_out, int out_size, void* d_ws, size_t ws_size,
                              hipStream_t stream) {
  const float* x      = (const float*)d_in[0];
  const float* ln1_g  = (const float*)d_in[1];
  const float* ln1_b  = (const float*)d_in[2];
  const float* w_attn = (const float*)d_in[3];
  const float* b_attn = (const float*)d_in[4];
  const float* w_proj = (const float*)d_in[5];
  const float* b_proj = (const float*)d_in[6];
  const float* ln2_g  = (const float*)d_in[7];
  const float* ln2_b  = (const float*)d_in[8];
  const float* w_fc   = (const float*)d_in[9];
  const float* b_fc   = (const float*)d_in[10];
  const float* w_fc2  = (const float*)d_in[11];
  const float* b_fc2  = (const float*)d_in[12];
  float* out = (float*)d_out;

  char* ws = (char*)d_ws;
  u16* wt_attn = (u16*)(ws + 0);          //  6291456 B
  u16* wt_proj = (u16*)(ws + 6291456);    //  2097152 B
  u16* wt_fc   = (u16*)(ws + 8388608);    //  8388608 B
  u16* wt_fc2  = (u16*)(ws + 16777216);   //  8388608 B
  u16* xn      = (u16*)(ws + 25165824);   // 16777216 B (LN1 out, reused for LN2 out)
  float* x2    = (float*)(ws + 41943040); // 33554432 B
  char* region = ws + 75497472;           // 83886080 B union region
  u16* qb = (u16*)(region);               // 16 MiB each
  u16* kb = (u16*)(region + 16777216);
  u16* vb = (u16*)(region + 33554432);
  u16* vt = (u16*)(region + 50331648);
  u16* ao = (u16*)(region + 67108864);
  u16* hm = (u16*)(region);               // 64 MiB, overlaps dead q/k/v/vt

  dim3 tb(32, 8);
  wt_transpose<<<dim3(3072 / 32, 1024 / 32), tb, 0, stream>>>(w_attn, wt_attn, 1024, 3072);
  wt_transpose<<<dim3(1024 / 32, 1024 / 32), tb, 0, stream>>>(w_proj, wt_proj, 1024, 1024);
  wt_transpose<<<dim3(4096 / 32, 1024 / 32), tb, 0, stream>>>(w_fc, wt_fc, 1024, 4096);
  wt_transpose<<<dim3(1024 / 32, 4096 / 32), tb, 0, stream>>>(w_fc2, wt_fc2, 4096, 1024);

  ln_kernel<<<8192, 256, 0, stream>>>(x, ln1_g, ln1_b, xn);

  gemm128<0><<<dim3(3072 / 128, 8192 / 128), 256, 0, stream>>>(
      xn, wt_attn, b_attn, 8192, 3072, 1024,
      nullptr, nullptr, nullptr, qb, kb, vb);

  v_transpose<<<dim3(32, 64), 256, 0, stream>>>(vb, vt);

  attn_kernel<<<dim3(8, 64), 256, 0, stream>>>(qb, kb, vt, ao);

  gemm128<1><<<dim3(1024 / 128, 8192 / 128), 256, 0, stream>>>(
      ao, wt_proj, b_proj, 8192, 1024, 1024,
      x2, nullptr, x, nullptr, nullptr, nullptr);

  ln_kernel<<<8192, 256, 0, stream>>>(x2, ln2_g, ln2_b, xn);

  gemm128<2><<<dim3(4096 / 128, 8192 / 128), 256, 0, stream>>>(
      xn, wt_fc, b_fc, 8192, 4096, 1024,
      nullptr, hm, nullptr, nullptr, nullptr, nullptr);

  gemm128<1><<<dim3(1024 / 128, 8192 / 128), 256, 0, stream>>>(
      hm, wt_fc2, b_fc2, 8192, 1024, 4096,
      out, nullptr, x2, nullptr, nullptr, nullptr);
}